// Round 7
// baseline (190.983 us; speedup 1.0000x reference)
//
#include <hip/hip_runtime.h>
#include <hip/hip_bf16.h>

#define N_NODES 40000
#define N_EDGES 640000
#define D_IN 512
#define D_OUT 128
#define BM 128
#define BK 64
#define CAPC 32          // packed 4B slots per row (P(Poisson(16)>32)~1e-4, ovf net)
#define OVF_MAX 4096
#define NB_GE 313        // gemm blocks (128-row tiles)
#define NB_SC 625        // scatter blocks: 640000 / (256*4)
#define EPT 4
#define CSTRIDE 16       // cursor stride in ints: one cursor per 64B line

typedef __attribute__((ext_vector_type(4))) float f32x4;
typedef __attribute__((ext_vector_type(8))) short bf16x8;
typedef __attribute__((ext_vector_type(4))) unsigned short us4;

static __device__ __forceinline__ unsigned short f2bf(float f) {
    unsigned int u = __float_as_uint(f);
    unsigned int r = u + 0x7fffu + ((u >> 16) & 1u);   // RNE
    return (unsigned short)(r >> 16);
}

// ---------------------------------------------------------------------------
// prep: zero cursor(padded) + ovf_cnt + ovf + bucket (7.75 MB, int4 stride)
// ---------------------------------------------------------------------------
__global__ __launch_bounds__(256) void prep_kernel(int4* __restrict__ zbase, int nz4)
{
    const int stride = 512 * 256;
    for (int i = blockIdx.x * 256 + threadIdx.x; i < nz4; i += stride)
        zbase[i] = make_int4(0, 0, 0, 0);
}

// ---------------------------------------------------------------------------
// fused: blocks [0, NB_GE) = LDS-tiled MFMA GEMM;
//        blocks [NB_GE, NB_GE+NB_SC) = bucket scatter (line-padded cursor).
// ---------------------------------------------------------------------------
__global__ __launch_bounds__(256) void fused_kernel(
    const float* __restrict__ x, const float* __restrict__ w,
    unsigned short* __restrict__ seq,
    const int* __restrict__ erow, const int* __restrict__ ecol,
    const float* __restrict__ eval, int* __restrict__ cursor,
    unsigned int* __restrict__ bucket, int* __restrict__ ovf_cnt,
    int4* __restrict__ ovf)
{
    if (blockIdx.x >= NB_GE) {
        // ---- scatter: 4 edges/thread; cursor padded to 1/cache-line ----
        const int base = (blockIdx.x - NB_GE) * (256 * EPT) + threadIdx.x;
        int r[EPT], c[EPT];
        float v[EPT];
        #pragma unroll
        for (int j = 0; j < EPT; j++) {
            int e = base + j * 256;
            r[j] = erow[e]; c[j] = ecol[e]; v[j] = eval[e];
        }
        int slot[EPT];
        #pragma unroll
        for (int j = 0; j < EPT; j++) slot[j] = atomicAdd(&cursor[r[j] * CSTRIDE], 1);
        #pragma unroll
        for (int j = 0; j < EPT; j++) {
            if (slot[j] < CAPC) {
                bucket[(size_t)r[j] * CAPC + slot[j]] =
                    ((unsigned int)f2bf(v[j]) << 16) | (unsigned int)c[j];
            } else {
                int o = atomicAdd(ovf_cnt, 1);
                if (o < OVF_MAX)
                    ovf[o] = make_int4(r[j], c[j], __float_as_int(v[j]), 0);
            }
        }
        return;
    }

    // ---- GEMM: seq[n][o] = sum_i x[n][i]*w[o][i], bf16 out (R3-proven) ----
    __shared__ unsigned short As[BM * BK];     // 16 KB
    __shared__ unsigned short Bs[D_OUT * BK];  // 16 KB

    const int tid = threadIdx.x;
    const int lane = tid & 63;
    const int wv = tid >> 6;
    const int block_row = blockIdx.x * BM;
    const int srow = tid >> 3;               // 0..31
    const int scol = (tid & 7) * 8;          // 0..56

    f32x4 ra[4][2], rb[4][2];                // prefetch regs

    auto issue_loads = [&](int k0) {
        #pragma unroll
        for (int p = 0; p < 4; ++p) {
            int gr = block_row + srow + p * 32; if (gr >= N_NODES) gr = N_NODES - 1;
            const float* sa = x + (size_t)gr * D_IN + k0 + scol;
            ra[p][0] = *(const f32x4*)sa;
            ra[p][1] = *(const f32x4*)(sa + 4);
            const float* sb = w + (size_t)(srow + p * 32) * D_IN + k0 + scol;
            rb[p][0] = *(const f32x4*)sb;
            rb[p][1] = *(const f32x4*)(sb + 4);
        }
    };

    f32x4 acc[2][8];
    #pragma unroll
    for (int i = 0; i < 2; i++)
        #pragma unroll
        for (int j = 0; j < 8; j++)
            acc[i][j] = f32x4{0.f, 0.f, 0.f, 0.f};

    issue_loads(0);

    for (int kt = 0; kt < D_IN / BK; ++kt) {
        __syncthreads();
        #pragma unroll
        for (int p = 0; p < 4; ++p) {
            int r = srow + p * 32;
            us4 h0, h1, g0, g1;
            #pragma unroll
            for (int q = 0; q < 4; q++) {
                h0[q] = f2bf(ra[p][0][q]); h1[q] = f2bf(ra[p][1][q]);
                g0[q] = f2bf(rb[p][0][q]); g1[q] = f2bf(rb[p][1][q]);
            }
            int off = (r * (BK * 2) + scol * 2) ^ ((r & 7) << 4);
            *(us4*)((char*)As + off)     = h0;
            *(us4*)((char*)As + off + 8) = h1;
            *(us4*)((char*)Bs + off)     = g0;
            *(us4*)((char*)Bs + off + 8) = g1;
        }
        if (kt < D_IN / BK - 1) issue_loads((kt + 1) * BK);  // overlap w/ MFMA
        __syncthreads();

        #pragma unroll
        for (int ks = 0; ks < 2; ++ks) {
            const int kb = ks * 32 + (lane >> 4) * 8;
            bf16x8 a[2], b[8];
            #pragma unroll
            for (int m = 0; m < 2; m++) {
                int r = wv * 32 + m * 16 + (lane & 15);
                int off = (r * (BK * 2) + kb * 2) ^ ((r & 7) << 4);
                a[m] = *(const bf16x8*)((const char*)As + off);
            }
            #pragma unroll
            for (int n = 0; n < 8; n++) {
                int r = n * 16 + (lane & 15);
                int off = (r * (BK * 2) + kb * 2) ^ ((r & 7) << 4);
                b[n] = *(const bf16x8*)((const char*)Bs + off);
            }
            #pragma unroll
            for (int m = 0; m < 2; m++)
                #pragma unroll
                for (int n = 0; n < 8; n++)
                    acc[m][n] = __builtin_amdgcn_mfma_f32_16x16x32_bf16(a[m], b[n], acc[m][n], 0, 0, 0);
        }
    }

    // C/D layout: col=lane&15, row=(lane>>4)*4+reg  [measured m89]
    #pragma unroll
    for (int m = 0; m < 2; m++) {
        #pragma unroll
        for (int r = 0; r < 4; r++) {
            int grow = block_row + wv * 32 + m * 16 + (lane >> 4) * 4 + r;
            if (grow < N_NODES) {
                #pragma unroll
                for (int n = 0; n < 8; n++) {
                    int col = n * 16 + (lane & 15);
                    seq[(size_t)grow * D_OUT + col] = f2bf(acc[m][n][r]);
                }
            }
        }
    }
}

// ---------------------------------------------------------------------------
// agg: one wave per row; lane owns cols {2l,2l+1}. 16-wide slot chunks (16
// independent gathers in flight); zeroed slots give exact 0, overrun-safe.
// ---------------------------------------------------------------------------
__global__ __launch_bounds__(256) void agg_kernel(
    const unsigned short* __restrict__ seq, const int* __restrict__ cursor,
    const unsigned int* __restrict__ bucket, const int* __restrict__ ovf_cnt,
    const int4* __restrict__ ovf, const float* __restrict__ bias,
    const float* __restrict__ alpha, float* __restrict__ out)
{
    const int row = blockIdx.x * 4 + (threadIdx.x >> 6);
    const int lane = threadIdx.x & 63;

    int cnt = cursor[row * CSTRIDE];
    int mx = cnt < CAPC ? cnt : CAPC;
    const unsigned int* bk = bucket + (size_t)row * CAPC;

    float a0 = 0.f, a1 = 0.f;
    for (int s = 0; s < mx; s += 16) {       // 16-chunk, overrun-safe (CAPC=32)
        #pragma unroll
        for (int j = 0; j < 16; j++) {
            unsigned int q = bk[s + j];
            float vv = __uint_as_float(q & 0xffff0000u);
            int col = q & 0xffff;
            unsigned int p = *(const unsigned int*)(seq + ((size_t)col << 7) + lane * 2);
            a0 += vv * __uint_as_float(p << 16);
            a1 += vv * __uint_as_float(p & 0xffff0000u);
        }
    }

    int on = *ovf_cnt;
    on = on < OVF_MAX ? on : OVF_MAX;
    for (int i = 0; i < on; ++i) {
        int4 t = ovf[i];
        if (t.x == row) {
            float vv = __int_as_float(t.z);
            unsigned int p = *(const unsigned int*)(seq + ((size_t)t.y << 7) + lane * 2);
            a0 += vv * __uint_as_float(p << 16);
            a1 += vv * __uint_as_float(p & 0xffff0000u);
        }
    }

    float al = alpha[0];
    float2 bi = *(const float2*)(bias + lane * 2);
    float r0 = a0 + bi.x;
    float r1 = a1 + bi.y;
    r0 = r0 > 0.f ? r0 : al * r0;
    r1 = r1 > 0.f ? r1 : al * r1;
    *(float2*)(out + (size_t)row * D_OUT + lane * 2) = make_float2(r0, r1);
}

// ---------------------------------------------------------------------------
extern "C" void kernel_launch(void* const* d_in, const int* in_sizes, int n_in,
                              void* d_out, int out_size, void* d_ws, size_t ws_size,
                              hipStream_t stream)
{
    (void)in_sizes; (void)n_in; (void)out_size; (void)ws_size;
    const float* x     = (const float*)d_in[0];
    const float* w     = (const float*)d_in[1];
    const float* bias  = (const float*)d_in[2];
    const float* alpha = (const float*)d_in[3];
    const float* eval  = (const float*)d_in[4];
    const int*   erow  = (const int*)d_in[5];
    const int*   ecol  = (const int*)d_in[6];
    float* out = (float*)d_out;

    char* ws = (char*)d_ws;
    unsigned short* seq  = (unsigned short*)ws;             // 10,240,000 B
    int*  cursor  = (int*)(ws + 10240000);                  //  2,560,000 B (64B-padded)
    int*  ovf_cnt = (int*)(ws + 12800000);                  //         16 B
    int4* ovf     = (int4*)(ws + 12800016);                 //     65,536 B
    unsigned int* bucket = (unsigned int*)(ws + 12865552);  //  5,120,000 B (tot ~18 MB)

    // zero region: cursor..bucket end = 7,745,552 B = 484,097 int4
    const int nz4 = 484097;
    prep_kernel<<<512, 256, 0, stream>>>((int4*)(ws + 10240000), nz4);
    fused_kernel<<<NB_GE + NB_SC, 256, 0, stream>>>(x, w, seq, erow, ecol, eval,
                                                    cursor, bucket, ovf_cnt, ovf);
    agg_kernel<<<N_NODES / 4, 256, 0, stream>>>(seq, cursor, bucket, ovf_cnt, ovf,
                                                bias, alpha, out);
}